// Round 5
// baseline (143.479 us; speedup 1.0000x reference)
//
#include <hip/hip_runtime.h>
#include <hip/hip_bf16.h>

// Problem: B=32, C=256, H=W=512, labels in [0,150).
// counts[b] = #unique label values in label[b]; out = mean_b( lse(cls[b]) - cls[b][counts[b]] )

#define B_SAMPLES 32
#define C_CLASSES 256
#define N_PER_SAMPLE (512 * 512)
#define CHUNKS 64                          // blocks per sample
#define PER_CHUNK (N_PER_SAMPLE / CHUNKS)  // 4096 elements
#define NBLOCKS (B_SAMPLES * CHUNKS)       // 2048

// ws layout: u32 counter at byte 0; u64 bitmap[32][4] at byte 256.
// Both zeroed by a 1.25 KB hipMemsetAsync each call (deterministic).
__global__ __launch_bounds__(256) void fused_kernel(
    const int* __restrict__ label, const float* __restrict__ cls,
    unsigned* __restrict__ counter, unsigned long long* __restrict__ bitmap,
    float* __restrict__ out) {
    const int b = blockIdx.x / CHUNKS;
    const int chunk = blockIdx.x % CHUNKS;
    const int t = threadIdx.x;

    __shared__ int flag[C_CLASSES];
    __shared__ unsigned ticket_sh;
    __shared__ int cnt_sh[B_SAMPLES];
    __shared__ float partial[4];

    flag[t] = 0;
    __syncthreads();

    // ---- Phase 1: presence bitmap for this chunk ----
    const int4* p = reinterpret_cast<const int4*>(
        label + (long)b * N_PER_SAMPLE + (long)chunk * PER_CHUNK);
    // All 4 dwordx4 loads in flight before any LDS store.
    const int4 v0 = p[0 * 256 + t];
    const int4 v1 = p[1 * 256 + t];
    const int4 v2 = p[2 * 256 + t];
    const int4 v3 = p[3 * 256 + t];

    flag[v0.x & 255] = 1; flag[v0.y & 255] = 1; flag[v0.z & 255] = 1; flag[v0.w & 255] = 1;
    flag[v1.x & 255] = 1; flag[v1.y & 255] = 1; flag[v1.z & 255] = 1; flag[v1.w & 255] = 1;
    flag[v2.x & 255] = 1; flag[v2.y & 255] = 1; flag[v2.z & 255] = 1; flag[v2.w & 255] = 1;
    flag[v3.x & 255] = 1; flag[v3.y & 255] = 1; flag[v3.z & 255] = 1; flag[v3.w & 255] = 1;
    __syncthreads();

    unsigned long long m = __ballot(flag[t] != 0);
    if ((t & 63) == 0 && m != 0ull) {
        atomicOr(&bitmap[b * 4 + (t >> 6)], m);   // device-scope
    }

    // Make this block's atomics globally visible, then take a ticket.
    __threadfence();
    __syncthreads();
    if (t == 0) ticket_sh = atomicAdd(counter, 1u);
    __syncthreads();
    if (ticket_sh != NBLOCKS - 1) return;   // only the LAST block continues

    // ---- CE tail (one block). Bitmap reads via identity-RMW: coherent across
    // XCDs and immune to stale L2 lines from the previous graph replay. ----
    if (t < 128) {
        const unsigned long long w64 = atomicOr(&bitmap[t], 0ull);  // [b=t>>2][word=t&3]
        int pc = __popcll(w64);
        pc += __shfl_xor(pc, 1);   // words are disjoint bit-ranges: popcount sums valid
        pc += __shfl_xor(pc, 2);
        if ((t & 3) == 0) cnt_sh[t >> 2] = pc;
    }
    __syncthreads();

    const int w = t >> 6;
    const int l = t & 63;

    float4 v[8];
    #pragma unroll
    for (int i = 0; i < 8; ++i) {
        v[i] = reinterpret_cast<const float4*>(cls)[(w * 8 + i) * 64 + l];
    }

    float nll = 0.0f;
    #pragma unroll
    for (int i = 0; i < 8; ++i) {
        const int bb = w * 8 + i;
        const float4 x = v[i];
        float mx = fmaxf(fmaxf(x.x, x.y), fmaxf(x.z, x.w));
        #pragma unroll
        for (int off = 32; off > 0; off >>= 1) mx = fmaxf(mx, __shfl_xor(mx, off));
        float e = expf(x.x - mx) + expf(x.y - mx) + expf(x.z - mx) + expf(x.w - mx);
        #pragma unroll
        for (int off = 32; off > 0; off >>= 1) e += __shfl_xor(e, off);
        const float lse = mx + logf(e);

        const int cnt = cnt_sh[bb];           // wave-uniform
        const int comp = cnt & 3;
        const float cand = (comp == 0) ? x.x : (comp == 1) ? x.y
                         : (comp == 2) ? x.z : x.w;
        const float target = __shfl(cand, cnt >> 2);
        nll += lse - target;
    }

    if (l == 0) partial[w] = nll;
    __syncthreads();
    if (t == 0) out[0] = (partial[0] + partial[1] + partial[2] + partial[3]) / (float)B_SAMPLES;
}

extern "C" void kernel_launch(void* const* d_in, const int* in_sizes, int n_in,
                              void* d_out, int out_size, void* d_ws, size_t ws_size,
                              hipStream_t stream) {
    const float* cls = (const float*)d_in[0];
    const int* label = (const int*)d_in[1];
    float* out = (float*)d_out;

    unsigned* counter = (unsigned*)d_ws;                                   // byte 0
    unsigned long long* bitmap = (unsigned long long*)((char*)d_ws + 256); // bytes 256..1280

    // Zero counter + bitmap (1.25 KB). Graph-capture-safe async memset.
    hipMemsetAsync(d_ws, 0, 256 + B_SAMPLES * 4 * sizeof(unsigned long long), stream);

    fused_kernel<<<NBLOCKS, 256, 0, stream>>>(label, cls, counter, bitmap, out);
}

// Round 6
// 17.416 us; speedup vs baseline: 8.2385x; 8.2385x over previous
//
#include <hip/hip_runtime.h>
#include <hip/hip_bf16.h>

// Problem: B=32, C=256, H=W=512, labels in [0,150).
// counts[b] = #unique label values in label[b]; out = mean_b( lse(cls[b]) - cls[b][counts[b]] )

#define B_SAMPLES 32
#define C_CLASSES 256
#define N_PER_SAMPLE (512 * 512)
#define CHUNKS 32                          // blocks per sample
#define PER_CHUNK (N_PER_SAMPLE / CHUNKS)  // 8192 elements

// Kernel 1: per-chunk 256-bit presence mask -> own ws slot (no atomics, no init).
// ws layout: u64 masks[B_SAMPLES * CHUNKS][4]
__global__ __launch_bounds__(256) void count_bitmap_kernel(
    const int* __restrict__ label, unsigned long long* __restrict__ masks) {
    const int b = blockIdx.x / CHUNKS;
    const int chunk = blockIdx.x % CHUNKS;
    const int t = threadIdx.x;

    __shared__ int flag[C_CLASSES];
    flag[t] = 0;
    __syncthreads();

    const int4* p = reinterpret_cast<const int4*>(
        label + (long)b * N_PER_SAMPLE + (long)chunk * PER_CHUNK);
    // Issue all 8 dwordx4 loads before any LDS store (keep them in flight).
    const int4 v0 = p[0 * 256 + t];
    const int4 v1 = p[1 * 256 + t];
    const int4 v2 = p[2 * 256 + t];
    const int4 v3 = p[3 * 256 + t];
    const int4 v4 = p[4 * 256 + t];
    const int4 v5 = p[5 * 256 + t];
    const int4 v6 = p[6 * 256 + t];
    const int4 v7 = p[7 * 256 + t];

    flag[v0.x & 255] = 1; flag[v0.y & 255] = 1; flag[v0.z & 255] = 1; flag[v0.w & 255] = 1;
    flag[v1.x & 255] = 1; flag[v1.y & 255] = 1; flag[v1.z & 255] = 1; flag[v1.w & 255] = 1;
    flag[v2.x & 255] = 1; flag[v2.y & 255] = 1; flag[v2.z & 255] = 1; flag[v2.w & 255] = 1;
    flag[v3.x & 255] = 1; flag[v3.y & 255] = 1; flag[v3.z & 255] = 1; flag[v3.w & 255] = 1;
    flag[v4.x & 255] = 1; flag[v4.y & 255] = 1; flag[v4.z & 255] = 1; flag[v4.w & 255] = 1;
    flag[v5.x & 255] = 1; flag[v5.y & 255] = 1; flag[v5.z & 255] = 1; flag[v5.w & 255] = 1;
    flag[v6.x & 255] = 1; flag[v6.y & 255] = 1; flag[v6.z & 255] = 1; flag[v6.w & 255] = 1;
    flag[v7.x & 255] = 1; flag[v7.y & 255] = 1; flag[v7.z & 255] = 1; flag[v7.w & 255] = 1;
    __syncthreads();

    unsigned long long m = __ballot(flag[t] != 0);
    if ((t & 63) == 0) {
        masks[(unsigned)blockIdx.x * 4 + (t >> 6)] = m;  // unconditional: overwrites poison
    }
}

// Kernel 2: OR-reduce chunk masks -> counts; CE in registers.
__global__ __launch_bounds__(256) void ce_kernel(
    const float* __restrict__ cls,
    const unsigned long long* __restrict__ masks,
    float* __restrict__ out) {
    const int t = threadIdx.x;
    const int w = t >> 6;
    const int l = t & 63;

    __shared__ int cnt_sh[B_SAMPLES];
    __shared__ float partial[4];

    // ---- Issue phase-B cls loads FIRST so they overlap phase A's mask loads ----
    float4 v[8];
    #pragma unroll
    for (int i = 0; i < 8; ++i) {
        const int b = w * 8 + i;
        v[i] = reinterpret_cast<const float4*>(cls)[b * 64 + l];
    }

    // ---- Phase A: 2 threads per (sample, word), 16 chunks each ----
    {
        const int item = t >> 1;           // 0..127
        const int sub  = t & 1;            // which half of the 32 chunks
        const int b    = item >> 2;        // 0..31
        const int word = item & 3;         // 0..3
        const unsigned long long* base =
            masks + ((unsigned)(b * CHUNKS + sub * 16)) * 4 + word;

        unsigned long long acc = 0ull;
        #pragma unroll
        for (int jj = 0; jj < 2; ++jj) {   // 2 batches of 8 independent loads
            const unsigned long long x0 = base[(jj * 8 + 0) * 4];
            const unsigned long long x1 = base[(jj * 8 + 1) * 4];
            const unsigned long long x2 = base[(jj * 8 + 2) * 4];
            const unsigned long long x3 = base[(jj * 8 + 3) * 4];
            const unsigned long long x4 = base[(jj * 8 + 4) * 4];
            const unsigned long long x5 = base[(jj * 8 + 5) * 4];
            const unsigned long long x6 = base[(jj * 8 + 6) * 4];
            const unsigned long long x7 = base[(jj * 8 + 7) * 4];
            acc |= ((x0 | x1) | (x2 | x3)) | ((x4 | x5) | (x6 | x7));
        }

        // MERGE the two sub-half ORs BEFORE popcount (union != popcount sum!)
        acc |= __shfl_xor(acc, 1);
        int p = __popcll(acc);
        // Words are disjoint 64-bit ranges -> popcount sums are valid across words.
        p += __shfl_xor(p, 2);   // combine words 0/1, 2/3
        p += __shfl_xor(p, 4);   // combine word pairs
        if ((t & 7) == 0) cnt_sh[t >> 3] = p;
    }
    __syncthreads();

    // ---- Phase B: wave w handles samples [8w, 8w+8) ----
    float nll = 0.0f;
    #pragma unroll
    for (int i = 0; i < 8; ++i) {
        const int b = w * 8 + i;
        const float4 x = v[i];
        float m = fmaxf(fmaxf(x.x, x.y), fmaxf(x.z, x.w));
        #pragma unroll
        for (int off = 32; off > 0; off >>= 1) m = fmaxf(m, __shfl_xor(m, off));
        float e = expf(x.x - m) + expf(x.y - m) + expf(x.z - m) + expf(x.w - m);
        #pragma unroll
        for (int off = 32; off > 0; off >>= 1) e += __shfl_xor(e, off);
        const float lse = m + logf(e);

        const int cnt = cnt_sh[b];            // wave-uniform
        const int comp = cnt & 3;
        const float cand = (comp == 0) ? x.x : (comp == 1) ? x.y
                         : (comp == 2) ? x.z : x.w;
        const float target = __shfl(cand, cnt >> 2);
        nll += lse - target;
    }

    if (l == 0) partial[w] = nll;
    __syncthreads();
    if (t == 0) out[0] = (partial[0] + partial[1] + partial[2] + partial[3]) / (float)B_SAMPLES;
}

extern "C" void kernel_launch(void* const* d_in, const int* in_sizes, int n_in,
                              void* d_out, int out_size, void* d_ws, size_t ws_size,
                              hipStream_t stream) {
    const float* cls = (const float*)d_in[0];
    const int* label = (const int*)d_in[1];
    float* out = (float*)d_out;
    unsigned long long* masks = (unsigned long long*)d_ws;  // 1024 * 4 * 8 = 32 KiB

    count_bitmap_kernel<<<B_SAMPLES * CHUNKS, 256, 0, stream>>>(label, masks);
    ce_kernel<<<1, 256, 0, stream>>>(cls, masks, out);
}

// Round 7
// 16.659 us; speedup vs baseline: 8.6129x; 1.0454x over previous
//
#include <hip/hip_runtime.h>
#include <hip/hip_bf16.h>

// Problem: B=32, C=256, H=W=512, labels in [0,150).
// counts[b] = #unique label values in label[b]; out = mean_b( lse(cls[b]) - cls[b][counts[b]] )

#define B_SAMPLES 32
#define C_CLASSES 256
#define N_PER_SAMPLE (512 * 512)
#define CHUNKS 16                          // blocks per sample
#define PER_CHUNK (N_PER_SAMPLE / CHUNKS)  // 16384 elements (64 KB)

// Kernel 1: per-chunk 256-bit presence mask -> own ws slot (no atomics, no init).
// ws layout: u64 masks[B_SAMPLES * CHUNKS][4]
__global__ __launch_bounds__(256) void count_bitmap_kernel(
    const int* __restrict__ label, unsigned long long* __restrict__ masks) {
    const int b = blockIdx.x / CHUNKS;
    const int chunk = blockIdx.x % CHUNKS;
    const int t = threadIdx.x;

    __shared__ int flag[C_CLASSES];
    flag[t] = 0;
    __syncthreads();

    const int4* p = reinterpret_cast<const int4*>(
        label + (long)b * N_PER_SAMPLE + (long)chunk * PER_CHUNK);

    // 16 independent dwordx4 loads in flight per thread.
    int4 v[16];
    #pragma unroll
    for (int i = 0; i < 16; ++i) v[i] = p[i * 256 + t];

    // Stores consume loads in order; compiler inserts incremental vmcnt waits,
    // so early stores overlap late loads.
    #pragma unroll
    for (int i = 0; i < 16; ++i) {
        flag[v[i].x & 255] = 1;
        flag[v[i].y & 255] = 1;
        flag[v[i].z & 255] = 1;
        flag[v[i].w & 255] = 1;
    }
    __syncthreads();

    unsigned long long m = __ballot(flag[t] != 0);
    if ((t & 63) == 0) {
        masks[(unsigned)blockIdx.x * 4 + (t >> 6)] = m;  // unconditional: overwrites poison
    }
}

// Kernel 2: OR-reduce chunk masks -> counts; CE in registers.
__global__ __launch_bounds__(256) void ce_kernel(
    const float* __restrict__ cls,
    const unsigned long long* __restrict__ masks,
    float* __restrict__ out) {
    const int t = threadIdx.x;
    const int w = t >> 6;
    const int l = t & 63;

    __shared__ int cnt_sh[B_SAMPLES];
    __shared__ float partial[4];

    // ---- Issue phase-B cls loads FIRST so they overlap phase A's mask loads ----
    float4 v[8];
    #pragma unroll
    for (int i = 0; i < 8; ++i) {
        const int b = w * 8 + i;
        v[i] = reinterpret_cast<const float4*>(cls)[b * 64 + l];
    }

    // ---- Phase A: one thread per (sample, word); OR all 16 chunks, then popcount ----
    if (t < 128) {
        const int b    = t >> 2;           // 0..31
        const int word = t & 3;            // 0..3
        const unsigned long long* base = masks + ((unsigned)(b * CHUNKS)) * 4 + word;

        unsigned long long acc = 0ull;
        #pragma unroll
        for (int jj = 0; jj < 2; ++jj) {   // 2 batches of 8 independent loads
            const unsigned long long x0 = base[(jj * 8 + 0) * 4];
            const unsigned long long x1 = base[(jj * 8 + 1) * 4];
            const unsigned long long x2 = base[(jj * 8 + 2) * 4];
            const unsigned long long x3 = base[(jj * 8 + 3) * 4];
            const unsigned long long x4 = base[(jj * 8 + 4) * 4];
            const unsigned long long x5 = base[(jj * 8 + 5) * 4];
            const unsigned long long x6 = base[(jj * 8 + 6) * 4];
            const unsigned long long x7 = base[(jj * 8 + 7) * 4];
            acc |= ((x0 | x1) | (x2 | x3)) | ((x4 | x5) | (x6 | x7));
        }

        // Full per-(sample,word) union formed BEFORE popcount.
        int p = __popcll(acc);
        // Words are disjoint 64-bit ranges -> popcount sums are valid across words.
        p += __shfl_xor(p, 1);
        p += __shfl_xor(p, 2);
        if ((t & 3) == 0) cnt_sh[t >> 2] = p;
    }
    __syncthreads();

    // ---- Phase B: wave w handles samples [8w, 8w+8) ----
    float nll = 0.0f;
    #pragma unroll
    for (int i = 0; i < 8; ++i) {
        const int b = w * 8 + i;
        const float4 x = v[i];
        float m = fmaxf(fmaxf(x.x, x.y), fmaxf(x.z, x.w));
        #pragma unroll
        for (int off = 32; off > 0; off >>= 1) m = fmaxf(m, __shfl_xor(m, off));
        float e = expf(x.x - m) + expf(x.y - m) + expf(x.z - m) + expf(x.w - m);
        #pragma unroll
        for (int off = 32; off > 0; off >>= 1) e += __shfl_xor(e, off);
        const float lse = m + logf(e);

        const int cnt = cnt_sh[b];            // wave-uniform
        const int comp = cnt & 3;
        const float cand = (comp == 0) ? x.x : (comp == 1) ? x.y
                         : (comp == 2) ? x.z : x.w;
        const float target = __shfl(cand, cnt >> 2);
        nll += lse - target;
    }

    if (l == 0) partial[w] = nll;
    __syncthreads();
    if (t == 0) out[0] = (partial[0] + partial[1] + partial[2] + partial[3]) / (float)B_SAMPLES;
}

extern "C" void kernel_launch(void* const* d_in, const int* in_sizes, int n_in,
                              void* d_out, int out_size, void* d_ws, size_t ws_size,
                              hipStream_t stream) {
    const float* cls = (const float*)d_in[0];
    const int* label = (const int*)d_in[1];
    float* out = (float*)d_out;
    unsigned long long* masks = (unsigned long long*)d_ws;  // 512 * 4 * 8 = 16 KiB

    count_bitmap_kernel<<<B_SAMPLES * CHUNKS, 256, 0, stream>>>(label, masks);
    ce_kernel<<<1, 256, 0, stream>>>(cls, masks, out);
}